// Round 1
// baseline (172.463 us; speedup 1.0000x reference)
//
#include <hip/hip_runtime.h>
#include <math.h>

// ---- problem constants ----
#define SEQ 64
#define NSAMP 16384
#define NHARM 32
#define NWS 512
#define NSTEP 256
#define BE 128            // B*E = 8*16
#define NFRAMES 8192      // BE * SEQ

#define PI_OVER_256 0.0122718463030851297f   // pi/256 (rotation step unit)

__device__ __forceinline__ float sin_rev(float x) {  // sin(2*pi*x)
  float r; asm("v_sin_f32 %0, %1" : "=v"(r) : "v"(x)); return r;
}
__device__ __forceinline__ float cos_rev(float x) {  // cos(2*pi*x)
  float r; asm("v_cos_f32 %0, %1" : "=v"(r) : "v"(x)); return r;
}
__device__ __forceinline__ float clip01(float v) { return fminf(fmaxf(v, 0.0f), 1.0f); }

// f0 (raw) + baseline -> normalized frequency f0n in [MIN_F0, MAX_F0]
__device__ __forceinline__ float f0_to_norm(float f0v, float bl) {
  const float NYQ = 11025.0f;
  const float MIN_F0 = 20.0f / 11025.0f;
  const float F0_DIFF = 780.0f / 11025.0f;
  float v = fminf(fmaxf(f0v, -0.5f), 0.5f);
  float erb = (0.108f * (bl * NYQ) + 24.7f) / NYQ;
  float fv = clip01(bl + v * erb);
  return MIN_F0 + fv * F0_DIFF;
}

// ---------------------------------------------------------------------------
// Kernel 1: per-(b,e) phase scan. qphase[be][t] = (sum_{m<=t} fund[m]) mod 2,
// in units of pi (half-cycles). f64 accumulation, f32 reduced store.
// Since harmonic factors are INTEGERS, factor*q mod 2 stays exact.
// ---------------------------------------------------------------------------
__global__ __launch_bounds__(256) void phase_k(const float* __restrict__ f0,
                                               const float* __restrict__ f0b,
                                               float* __restrict__ qphase) {
  const int be = blockIdx.x;
  const int tid = threadIdx.x;
  __shared__ float f0n_s[SEQ];
  __shared__ double tsum[256];
  __shared__ float qbuf[4096];
  const float bl = f0b[be];
  if (tid < SEQ) f0n_s[tid] = f0_to_norm(f0[be * SEQ + tid], bl);
  __syncthreads();

  double carry = 0.0;
  for (int ch = 0; ch < 4; ++ch) {
    const int base = ch * 4096 + tid * 16;
    float fv[16];
    double loc = 0.0;
#pragma unroll
    for (int i = 0; i < 16; ++i) {
      int t = base + i;
      float pos = ((float)t + 0.5f) * (1.0f / 256.0f) - 0.5f;
      pos = fminf(fmaxf(pos, 0.0f), 63.0f);
      int i0 = (int)pos;
      int i1 = min(i0 + 1, 63);
      float w = pos - (float)i0;
      float fund = f0n_s[i0] * (1.0f - w) + f0n_s[i1] * w;
      fv[i] = fund;
      loc += (double)fund;
    }
    tsum[tid] = loc;
    __syncthreads();
    // Hillis-Steele inclusive scan over 256 thread partials
    for (int off = 1; off < 256; off <<= 1) {
      double add = (tid >= off) ? tsum[tid - off] : 0.0;
      __syncthreads();
      tsum[tid] += add;
      __syncthreads();
    }
    double prefix = carry + ((tid > 0) ? tsum[tid - 1] : 0.0);
    double total = tsum[255];
    double run = prefix;
#pragma unroll
    for (int i = 0; i < 16; ++i) {
      run += (double)fv[i];
      double r = run - 2.0 * floor(run * 0.5);   // mod 2 -> [0,2)
      qbuf[tid * 16 + i] = (float)r;
    }
    carry += total;
    __syncthreads();
    // coalesced write-out of the chunk
    for (int i = 0; i < 16; ++i)
      qphase[(size_t)be * NSAMP + ch * 4096 + i * 256 + tid] = qbuf[i * 256 + tid];
    __syncthreads();
  }
}

// ---------------------------------------------------------------------------
// Kernel 2: band-filtered noise, one block per frame (be*64+f).
// Windowed direct DFT restricted to bins where the Gaussian filter is
// non-negligible (khi <= ~122 always), then truncated inverse DFT.
// Rotation recurrences: no trig tables, xw/Af/Bf LDS reads are broadcasts.
// ---------------------------------------------------------------------------
__global__ __launch_bounds__(256) void noise_k(const float* __restrict__ frames,
                                               const float* __restrict__ f0,
                                               const float* __restrict__ nstd,
                                               const float* __restrict__ f0b,
                                               float* __restrict__ Y) {
  const int bid = blockIdx.x;   // be*64 + fr
  const int be = bid >> 6;
  const int fr = bid & 63;
  const int tid = threadIdx.x;
  const float F0_DIFF = 780.0f / 11025.0f;

  __shared__ float xw[NWS];
  __shared__ float SrH[2][128], SiH[2][128];
  __shared__ float Af[128], Bf[128];

  // load + Hann window
  for (int n = tid; n < NWS; n += 256) {
    float x = frames[(size_t)bid * NWS + n];
    float w = 0.5f - 0.5f * cos_rev((float)n * (1.0f / 512.0f));
    xw[n] = x * w;
  }

  const float bl = f0b[be];
  const float mu = f0_to_norm(f0[be * SEQ + fr], bl);
  const float sd = fminf(fmaxf(nstd[be * SEQ + fr], 1e-12f), 1.0f) * F0_DIFF;
  const float mub = mu * 256.0f, sdb = sd * 256.0f;
  int klo = max(0, (int)floorf(mub - 5.7f * sdb));
  int khi = min(256, (int)ceilf(mub + 5.7f * sdb));
  if (khi - klo > 127) khi = klo + 127;  // safety cap (unreachable: khi<=122)
  const int nb = khi - klo + 1;
  __syncthreads();

  // ---- forward DFT: bin m = tid&127 (k = klo+m), half = tid>>7 over n ----
  {
    const int m = tid & 127, half = tid >> 7;
    if (m < nb) {
      const int k = klo + m;
      float sD, cD;
      sincosf((float)k * PI_OVER_256, &sD, &cD);          // step 2*pi*k/512
      float c = (half && (k & 1)) ? -1.0f : 1.0f;          // cos(pi*k*half)
      float s = 0.0f;
      float Sr = 0.0f, Si = 0.0f;
      const int b0 = half * 256;
      for (int n = 0; n < 256; ++n) {
        float x = xw[b0 + n];                              // LDS broadcast
        Sr = fmaf(x, c, Sr);
        Si = fmaf(x, s, Si);
        float nc = c * cD - s * sD;
        float ns = s * cD + c * sD;
        c = nc; s = ns;
      }
      SrH[half][m] = Sr;
      SiH[half][m] = Si;
    }
  }
  __syncthreads();

  // ---- filter + fold constants: A = c_k * filt * Sr / 512, B likewise ----
  if (tid < nb) {
    const int k = klo + tid;
    float Sr = SrH[0][tid] + SrH[1][tid];
    float Si = SiH[0][tid] + SiH[1][tid];
    float z = ((float)k * (1.0f / 256.0f) - mu) / sd;
    float fk = expf(-0.5f * z * z);
    float cf = (k == 0) ? 1.0f : 2.0f;
    float sc = cf * fk * (1.0f / 512.0f);
    Af[tid] = sc * Sr;
    Bf[tid] = sc * Si;
  }
  __syncthreads();

  // ---- inverse DFT: sample n = tid and n+256 via parity trick ----
  {
    const int n = tid;
    float sD, cD;
    sincosf((float)n * PI_OVER_256, &sD, &cD);            // step 2*pi*n/512
    int j0 = (n * klo) & 511;
    float s, c;
    sincosf((float)j0 * PI_OVER_256, &s, &c);             // start 2*pi*n*klo/512
    float y1 = 0.0f, y2 = 0.0f;
    float pm = (klo & 1) ? -1.0f : 1.0f;
    for (int j = 0; j < nb; ++j) {
      float u = fmaf(Af[j], c, Bf[j] * s);                // LDS broadcast
      y1 += u;
      y2 = fmaf(pm, u, y2);
      pm = -pm;
      float nc = c * cD - s * sD;
      float ns = s * cD + c * sD;
      c = nc; s = ns;
    }
    size_t yb = (size_t)bid * NWS;
    Y[yb + n] = y1;          // y[n]     = even + odd bins
    Y[yb + n + 256] = y2;    // y[n+256] = even - odd bins
  }
}

// ---------------------------------------------------------------------------
// Kernel 3: oscillator bank + overlap-add + mix. One block per (b,e).
// ---------------------------------------------------------------------------
__global__ __launch_bounds__(256) void final_k(const float* __restrict__ oenv_g,
                                               const float* __restrict__ oscenv_g,
                                               const float* __restrict__ henv_g,
                                               const float* __restrict__ qphase,
                                               const float* __restrict__ Y,
                                               float* __restrict__ out) {
  const int be = blockIdx.x;
  const int tid = threadIdx.x;
  __shared__ float oenv[SEQ], oscE[SEQ];
  __shared__ float qe[NHARM][SEQ];
  if (tid < SEQ) {
    oenv[tid] = clip01(oenv_g[be * SEQ + tid]);
    oscE[tid] = clip01(oscenv_g[be * SEQ + tid]);
  }
  __syncthreads();
  for (int i = tid; i < NHARM * SEQ; i += 256) {
    int h = i >> 6, s = i & 63;
    qe[h][s] = oscE[s] * clip01(henv_g[(size_t)be * (NHARM * SEQ) + i]);
  }
  __syncthreads();

  for (int it = 0; it < 64; ++it) {
    const int t = it * 256 + tid;
    float pos = ((float)t + 0.5f) * (1.0f / 256.0f) - 0.5f;
    pos = fminf(fmaxf(pos, 0.0f), 63.0f);
    int i0 = (int)pos;
    int i1 = min(i0 + 1, 63);
    float w = pos - (float)i0;

    float q = qphase[(size_t)be * NSAMP + t];              // phase mod 2, pi units
    float xf = q * 0.5f;
    float osc = sin_rev(xf - floorf(xf)) * (oscE[i0] * (1.0f - w) + oscE[i1] * w);
#pragma unroll
    for (int h = 0; h < NHARM; ++h) {
      float cph = (float)(h + 2) * q * 0.5f;               // <= 33 revolutions
      float sh = sin_rev(cph - floorf(cph));
      float he = qe[h][i0] * (1.0f - w) + qe[h][i1] * w;
      osc = fmaf(sh, he, osc);
    }
    float mix = oenv[i0] * (1.0f - w) + oenv[i1] * w;

    // overlap-add: frame it first half + frame it-1 second half
    float noise = Y[((size_t)be * SEQ + it) * NWS + tid];
    if (it > 0) noise += Y[((size_t)be * SEQ + (it - 1)) * NWS + 256 + tid];

    out[(size_t)be * NSAMP + t] = fmaf(osc, mix, noise * (1.0f - mix));
  }
}

// ---------------------------------------------------------------------------
extern "C" void kernel_launch(void* const* d_in, const int* in_sizes, int n_in,
                              void* d_out, int out_size, void* d_ws, size_t ws_size,
                              hipStream_t stream) {
  const float* f0           = (const float*)d_in[0];
  const float* overall_env  = (const float*)d_in[1];
  const float* osc_env      = (const float*)d_in[2];
  // d_in[3] = noise_env: unused by the reference
  const float* harm_env     = (const float*)d_in[4];
  const float* noise_std    = (const float*)d_in[5];
  const float* f0_base      = (const float*)d_in[6];
  const float* noise_frames = (const float*)d_in[7];
  float* out = (float*)d_out;

  // workspace: qphase (128*16384 f32 = 8.4MB) + Y frames (8192*512 f32 = 16.8MB)
  float* qphase = (float*)d_ws;
  float* Y = qphase + (size_t)BE * NSAMP;

  phase_k<<<BE, 256, 0, stream>>>(f0, f0_base, qphase);
  noise_k<<<NFRAMES, 256, 0, stream>>>(noise_frames, f0, noise_std, f0_base, Y);
  final_k<<<BE, 256, 0, stream>>>(overall_env, osc_env, harm_env, qphase, Y, out);
}

// Round 2
// 68.016 us; speedup vs baseline: 2.5356x; 2.5356x over previous
//
#include <hip/hip_runtime.h>
#include <math.h>

// ---- problem constants ----
#define SEQ 64
#define NSAMP 16384
#define NHARM 32
#define NWS 512
#define NSTEP 256
#define BE 128            // B*E = 8*16
#define NFRAMES 8192      // BE * SEQ

__device__ __forceinline__ float sin_rev(float x) {  // sin(2*pi*x)
  float r; asm("v_sin_f32 %0, %1" : "=v"(r) : "v"(x)); return r;
}
__device__ __forceinline__ float cos_rev(float x) {  // cos(2*pi*x)
  float r; asm("v_cos_f32 %0, %1" : "=v"(r) : "v"(x)); return r;
}
__device__ __forceinline__ float clip01(float v) { return fminf(fmaxf(v, 0.0f), 1.0f); }

// f0 (raw) + baseline -> normalized frequency f0n in [MIN_F0, MAX_F0]
__device__ __forceinline__ float f0_to_norm(float f0v, float bl) {
  const float NYQ = 11025.0f;
  const float MIN_F0 = 20.0f / 11025.0f;
  const float F0_DIFF = 780.0f / 11025.0f;
  float v = fminf(fmaxf(f0v, -0.5f), 0.5f);
  float erb = (0.108f * (bl * NYQ) + 24.7f) / NYQ;
  float fv = clip01(bl + v * erb);
  return MIN_F0 + fv * F0_DIFF;
}

// ---------------------------------------------------------------------------
// Kernel 1: per-(b,e) phase scan. qphase[be][t] = (sum_{m<=t} fund[m]) mod 2,
// in units of pi (half-cycles). f64 accumulation, f32 reduced store.
// ---------------------------------------------------------------------------
__global__ __launch_bounds__(256) void phase_k(const float* __restrict__ f0,
                                               const float* __restrict__ f0b,
                                               float* __restrict__ qphase) {
  const int be = blockIdx.x;
  const int tid = threadIdx.x;
  __shared__ float f0n_s[SEQ];
  __shared__ double tsum[256];
  __shared__ float qbuf[4096];
  const float bl = f0b[be];
  if (tid < SEQ) f0n_s[tid] = f0_to_norm(f0[be * SEQ + tid], bl);
  __syncthreads();

  double carry = 0.0;
  for (int ch = 0; ch < 4; ++ch) {
    const int base = ch * 4096 + tid * 16;
    float fv[16];
    double loc = 0.0;
#pragma unroll
    for (int i = 0; i < 16; ++i) {
      int t = base + i;
      float pos = ((float)t + 0.5f) * (1.0f / 256.0f) - 0.5f;
      pos = fminf(fmaxf(pos, 0.0f), 63.0f);
      int i0 = (int)pos;
      int i1 = min(i0 + 1, 63);
      float w = pos - (float)i0;
      float fund = f0n_s[i0] * (1.0f - w) + f0n_s[i1] * w;
      fv[i] = fund;
      loc += (double)fund;
    }
    tsum[tid] = loc;
    __syncthreads();
    for (int off = 1; off < 256; off <<= 1) {
      double add = (tid >= off) ? tsum[tid - off] : 0.0;
      __syncthreads();
      tsum[tid] += add;
      __syncthreads();
    }
    double prefix = carry + ((tid > 0) ? tsum[tid - 1] : 0.0);
    double total = tsum[255];
    double run = prefix;
#pragma unroll
    for (int i = 0; i < 16; ++i) {
      run += (double)fv[i];
      double r = run - 2.0 * floor(run * 0.5);   // mod 2 -> [0,2)
      qbuf[tid * 16 + i] = (float)r;
    }
    carry += total;
    __syncthreads();
    for (int i = 0; i < 16; ++i)
      qphase[(size_t)be * NSAMP + ch * 4096 + i * 256 + tid] = qbuf[i * 256 + tid];
    __syncthreads();
  }
}

// ---------------------------------------------------------------------------
// Kernel 2: band-filtered noise via Goertzel (fwd) + even/odd Goertzel (inv).
// One block per frame. All twiddle phases are integer multiples of pi/256,
// evaluated as v_sin/v_cos of (int&511)/512 revolutions (exact reduction).
// ---------------------------------------------------------------------------
__global__ __launch_bounds__(256) void noise_k(const float* __restrict__ frames,
                                               const float* __restrict__ f0,
                                               const float* __restrict__ nstd,
                                               const float* __restrict__ f0b,
                                               float* __restrict__ Y) {
  const int bid = blockIdx.x;   // be*64 + fr
  const int be = bid >> 6;
  const int fr = bid & 63;
  const int tid = threadIdx.x;
  const float F0_DIFF = 780.0f / 11025.0f;

  __shared__ __align__(16) float xw[NWS];
  __shared__ float tfr[128][2], tfi[128][2];
  __shared__ __align__(16) float2 AB2[132];

  // load + Hann window
  for (int n = tid; n < NWS; n += 256) {
    float x = frames[(size_t)bid * NWS + n];
    float w = 0.5f - 0.5f * cos_rev((float)n * (1.0f / 512.0f));
    xw[n] = x * w;
  }

  const float bl = f0b[be];
  const float mu = f0_to_norm(f0[be * SEQ + fr], bl);
  const float sd = fminf(fmaxf(nstd[be * SEQ + fr], 1e-12f), 1.0f) * F0_DIFF;
  const float mub = mu * 256.0f, sdb = sd * 256.0f;
  int klo = max(0, (int)floorf(mub - 4.2f * sdb));
  int khi = min(256, (int)ceilf(mub + 4.2f * sdb));
  if (khi - klo > 127) khi = klo + 127;  // safety cap (unreachable at 4.2 sigma)
  const int nb = khi - klo + 1;
  __syncthreads();

  // ---- forward Goertzel: thread (bin j = tid>>1, half = tid&1) ----
  {
    const int j = tid >> 1, half = tid & 1;
    if (j < nb) {
      const int k = klo + j;
      const float cw = cos_rev((float)k * (1.0f / 512.0f));  // cos(pi*k/256)
      const float sw = sin_rev((float)k * (1.0f / 512.0f));
      const float C = 2.0f * cw;
      const float4* x4 = (const float4*)xw + half * 64;
      float s1 = 0.0f, s2 = 0.0f;
      for (int i = 0; i < 64; ++i) {
        float4 x = x4[i];
        float t;
        t = fmaf(C, s1, x.x) - s2; s2 = s1; s1 = t;
        t = fmaf(C, s1, x.y) - s2; s2 = s1; s1 = t;
        t = fmaf(C, s1, x.z) - s2; s2 = s1; s1 = t;
        t = fmaf(C, s1, x.w) - s2; s2 = s1; s1 = t;
      }
      tfr[j][half] = fmaf(cw, s1, -s2);   // (-1)^k * Re{X_half}
      tfi[j][half] = sw * s1;             // (-1)^(k+1) * (-Im) bookkeeping below
    }
  }
  __syncthreads();

  // ---- filter + fold: Af = sc*Sr, Bf = sc*Si (Si = +sum x sin(wn) convention)
  if (tid < nb) {
    const int k = klo + tid;
    const float sgn = (k & 1) ? -1.0f : 1.0f;
    float Sr = tfr[tid][1] + sgn * tfr[tid][0];
    float Si = -(tfi[tid][1] + sgn * tfi[tid][0]);
    float z = ((float)k * (1.0f / 256.0f) - mu) / sd;
    float fk = expf(-0.5f * z * z);
    float cf = (k == 0) ? 1.0f : 2.0f;
    float sc = cf * fk * (1.0f / 512.0f);
    AB2[tid] = make_float2(sc * Sr, sc * Si);
  }
  if (tid >= nb && tid < nb + 4) AB2[tid] = make_float2(0.0f, 0.0f);  // zero-pad
  __syncthreads();

  // ---- inverse: thread n = tid -> y[n], y[n+256] via E/O split Goertzel ----
  {
    const int n = tid;
    const int M0 = (nb + 1) >> 1;
    const int M = (M0 + 1) & ~1;          // force even (zero-padded)
    const int a2 = (2 * n) & 511;         // psi = 2*pi*(2n)/512
    const float cpsi = cos_rev((float)a2 * (1.0f / 512.0f));
    const float spsi = sin_rev((float)a2 * (1.0f / 512.0f));
    const float C2 = 2.0f * cpsi;
    const float4* ab4 = (const float4*)AB2;
    float er1 = 0.0f, er2 = 0.0f, ei1 = 0.0f, ei2 = 0.0f;
    float or1 = 0.0f, or2 = 0.0f, oi1 = 0.0f, oi2 = 0.0f;
    for (int m = 0; m < M; m += 2) {
      float4 qa = ab4[m];
      float4 qb = ab4[m + 1];
      er2 = fmaf(C2, er1, qa.x) - er2;
      ei2 = fmaf(C2, ei1, -qa.y) - ei2;
      or2 = fmaf(C2, or1, qa.z) - or2;
      oi2 = fmaf(C2, oi1, -qa.w) - oi2;
      er1 = fmaf(C2, er2, qb.x) - er1;
      ei1 = fmaf(C2, ei2, -qb.y) - ei1;
      or1 = fmaf(C2, or2, qb.z) - or1;
      oi1 = fmaf(C2, oi2, -qb.w) - oi1;
    }
    // P = e^{i*psi*(M-1)} * (s_{M-1} - e^{i*psi} s_{M-2})
    const int aE = (a2 * (M - 1)) & 511;
    const float ca = cos_rev((float)aE * (1.0f / 512.0f));
    const float sa = sin_rev((float)aE * (1.0f / 512.0f));
    float wEr = er1 - (cpsi * er2 - spsi * ei2);
    float wEi = ei1 - (cpsi * ei2 + spsi * er2);
    float PEr = ca * wEr - sa * wEi;
    float PEi = ca * wEi + sa * wEr;
    float wOr = or1 - (cpsi * or2 - spsi * oi2);
    float wOi = oi1 - (cpsi * oi2 + spsi * or2);
    float POr = ca * wOr - sa * wOi;
    float POi = ca * wOi + sa * wOr;
    const float cphi = cos_rev((float)n * (1.0f / 512.0f));   // phi = pi*n/256
    const float sphi = sin_rev((float)n * (1.0f / 512.0f));
    float Qr = cphi * POr - sphi * POi;
    float Qi = cphi * POi + sphi * POr;
    const int aK = (klo * n) & 511;
    const float ck = cos_rev((float)aK * (1.0f / 512.0f));
    const float sk = sin_rev((float)aK * (1.0f / 512.0f));
    float y1 = ck * (PEr + Qr) - sk * (PEi + Qi);
    float y2 = ck * (PEr - Qr) - sk * (PEi - Qi);
    if (klo & 1) y2 = -y2;
    size_t yb = (size_t)bid * NWS;
    Y[yb + n] = y1;
    Y[yb + n + 256] = y2;
  }
}

// ---------------------------------------------------------------------------
// Kernel 3: oscillator bank (Chebyshev harmonic recurrence) + OLA + mix.
// 512 blocks: (b,e) x 4 sample-quarters.
// ---------------------------------------------------------------------------
__global__ __launch_bounds__(256) void final_k(const float* __restrict__ oenv_g,
                                               const float* __restrict__ oscenv_g,
                                               const float* __restrict__ henv_g,
                                               const float* __restrict__ qphase,
                                               const float* __restrict__ Y,
                                               float* __restrict__ out) {
  const int blk = blockIdx.x;
  const int be = blk >> 2, qtr = blk & 3;
  const int tid = threadIdx.x;
  __shared__ float oenv[SEQ], oscE[SEQ];
  __shared__ __align__(16) float4 qe4[8 * SEQ];  // qe4[hq*64+s] = qe[4hq..4hq+3][s]
  if (tid < SEQ) {
    oenv[tid] = clip01(oenv_g[be * SEQ + tid]);
    oscE[tid] = clip01(oscenv_g[be * SEQ + tid]);
  }
  __syncthreads();
  for (int idx = tid; idx < 8 * SEQ; idx += 256) {
    int hq = idx >> 6, s = idx & 63;
    const float* hb = henv_g + (size_t)be * (NHARM * SEQ) + (4 * hq) * SEQ + s;
    float e = oscE[s];
    qe4[idx] = make_float4(e * clip01(hb[0]), e * clip01(hb[64]),
                           e * clip01(hb[128]), e * clip01(hb[192]));
  }
  __syncthreads();

  for (int ii = 0; ii < 16; ++ii) {
    const int it = qtr * 16 + ii;
    const int t = it * 256 + tid;
    float pos = ((float)t + 0.5f) * (1.0f / 256.0f) - 0.5f;
    pos = fminf(fmaxf(pos, 0.0f), 63.0f);
    int i0 = (int)pos;
    int i1 = min(i0 + 1, 63);
    float w = pos - (float)i0;

    float q = qphase[(size_t)be * NSAMP + t];  // phase mod 2, pi units
    float x = q * 0.5f;                        // revolutions in [0,1)
    float sb = sin_rev(x);                     // sin(theta)
    float cb = cos_rev(x);
    float C = 2.0f * cb;

    float fund = sb * (oscE[i0] * (1.0f - w) + oscE[i1] * w);

    // harmonics h = 2..33 via Chebyshev: s_{h+1} = C*s_h - s_{h-1}
    float d0 = 0.0f, d1 = 0.0f;
    float sp = sb;            // s_1
    float scur = C * sb;      // s_2
#pragma unroll
    for (int hq = 0; hq < 8; ++hq) {
      float4 qa = qe4[hq * 64 + i0];
      float4 qb = qe4[hq * 64 + i1];
      d0 = fmaf(scur, qa.x, d0); d1 = fmaf(scur, qb.x, d1);
      sp = fmaf(C, scur, -sp);
      d0 = fmaf(sp, qa.y, d0);   d1 = fmaf(sp, qb.y, d1);
      scur = fmaf(C, sp, -scur);
      d0 = fmaf(scur, qa.z, d0); d1 = fmaf(scur, qb.z, d1);
      sp = fmaf(C, scur, -sp);
      d0 = fmaf(sp, qa.w, d0);   d1 = fmaf(sp, qb.w, d1);
      scur = fmaf(C, sp, -scur);
    }
    float osc = fund + d0 * (1.0f - w) + d1 * w;
    float mix = oenv[i0] * (1.0f - w) + oenv[i1] * w;

    float noise = Y[((size_t)be * SEQ + it) * NWS + tid];
    if (it > 0) noise += Y[((size_t)be * SEQ + (it - 1)) * NWS + 256 + tid];

    out[(size_t)be * NSAMP + t] = fmaf(osc, mix, noise * (1.0f - mix));
  }
}

// ---------------------------------------------------------------------------
extern "C" void kernel_launch(void* const* d_in, const int* in_sizes, int n_in,
                              void* d_out, int out_size, void* d_ws, size_t ws_size,
                              hipStream_t stream) {
  const float* f0           = (const float*)d_in[0];
  const float* overall_env  = (const float*)d_in[1];
  const float* osc_env      = (const float*)d_in[2];
  // d_in[3] = noise_env: unused by the reference
  const float* harm_env     = (const float*)d_in[4];
  const float* noise_std    = (const float*)d_in[5];
  const float* f0_base      = (const float*)d_in[6];
  const float* noise_frames = (const float*)d_in[7];
  float* out = (float*)d_out;

  float* qphase = (float*)d_ws;                       // 8.4 MB
  float* Y = qphase + (size_t)BE * NSAMP;             // 16.8 MB

  phase_k<<<BE, 256, 0, stream>>>(f0, f0_base, qphase);
  noise_k<<<NFRAMES, 256, 0, stream>>>(noise_frames, f0, noise_std, f0_base, Y);
  final_k<<<512, 256, 0, stream>>>(overall_env, osc_env, harm_env, qphase, Y, out);
}